// Round 6
// baseline (263.323 us; speedup 1.0000x reference)
//
#include <hip/hip_runtime.h>

// Problem constants: B=8, M=N=256, D=512
#define INFV 1.0e8f

// Raw HW transcendentals: v_exp_f32 is 2^x, v_log_f32 is log2(x).
#define EXP2F(x) __builtin_amdgcn_exp2f(x)
#define LOG2F(x) __builtin_amdgcn_logf(x)

__device__ __forceinline__ void ld4(float d[4], const float* p) {
  float4 v = *(const float4*)p;
  d[0] = v.x; d[1] = v.y; d[2] = v.z; d[3] = v.w;
}

// ---------------------------------------------------------------------------
// Kernel 1: inverse row norms.  rn = 1 / max(||row||, 1e-8)
// ---------------------------------------------------------------------------
__global__ void __launch_bounds__(256) norms_kernel(const float* __restrict__ x,
                                                    const float* __restrict__ y,
                                                    float* __restrict__ rnx,
                                                    float* __restrict__ rny) {
  int g = blockIdx.x * 4 + (threadIdx.x >> 6);
  int lane = threadIdx.x & 63;
  const float* src; float* dst; int row;
  if (g < 2048) { src = x; dst = rnx; row = g; }
  else          { src = y; dst = rny; row = g - 2048; }
  const float* p = src + (size_t)row * 512;
  float4 v0 = *(const float4*)(p + lane * 4);
  float4 v1 = *(const float4*)(p + 256 + lane * 4);
  float s = v0.x*v0.x + v0.y*v0.y + v0.z*v0.z + v0.w*v0.w
          + v1.x*v1.x + v1.y*v1.y + v1.z*v1.z + v1.w*v1.w;
#pragma unroll
  for (int o = 32; o > 0; o >>= 1) s += __shfl_xor(s, o, 64);
  if (lane == 0) dst[row] = 1.0f / fmaxf(sqrtf(s), 1e-8f);
}

// ---------------------------------------------------------------------------
// Kernel 2: cost GEMM -> COLUMN-MAJOR layout costC[b][n][m] (stride 256).
// ---------------------------------------------------------------------------
__global__ void __launch_bounds__(256) cost_gemm(const float* __restrict__ x,
                                                 const float* __restrict__ y,
                                                 const float* __restrict__ rnx,
                                                 const float* __restrict__ rny,
                                                 float* __restrict__ costC) {
  int b = blockIdx.z, mt = blockIdx.y, nt = blockIdx.x;
  int m0 = mt * 64, n0 = nt * 64;
  __shared__ float Xs[16][68];
  __shared__ float Ys[16][68];
  int tid = threadIdx.x;
  int row = tid >> 2, cq = tid & 3;
  int tx = tid & 15, ty = tid >> 4;
  const float* xb = x + ((size_t)b * 256 + m0) * 512;
  const float* yb = y + ((size_t)b * 256 + n0) * 512;
  float acc[4][4] = {};
  for (int k0 = 0; k0 < 512; k0 += 16) {
    float4 xv = *(const float4*)(xb + (size_t)row * 512 + k0 + cq * 4);
    float4 yv = *(const float4*)(yb + (size_t)row * 512 + k0 + cq * 4);
    __syncthreads();
    Xs[cq*4+0][row] = xv.x; Xs[cq*4+1][row] = xv.y;
    Xs[cq*4+2][row] = xv.z; Xs[cq*4+3][row] = xv.w;
    Ys[cq*4+0][row] = yv.x; Ys[cq*4+1][row] = yv.y;
    Ys[cq*4+2][row] = yv.z; Ys[cq*4+3][row] = yv.w;
    __syncthreads();
#pragma unroll
    for (int kk = 0; kk < 16; ++kk) {
      float4 av = *(const float4*)(&Xs[kk][ty * 4]);
      float4 bv = *(const float4*)(&Ys[kk][tx * 4]);
      float ar[4] = {av.x, av.y, av.z, av.w};
      float br[4] = {bv.x, bv.y, bv.z, bv.w};
#pragma unroll
      for (int r = 0; r < 4; ++r)
#pragma unroll
        for (int c = 0; c < 4; ++c)
          acc[r][c] += ar[r] * br[c];
    }
  }
  float rx[4], ry[4];
#pragma unroll
  for (int r = 0; r < 4; ++r) rx[r] = rnx[b * 256 + m0 + ty * 4 + r];
#pragma unroll
  for (int c = 0; c < 4; ++c) ry[c] = rny[b * 256 + n0 + tx * 4 + c];
  float* cb = costC + (size_t)b * 65536;
#pragma unroll
  for (int c = 0; c < 4; ++c) {
    int n = n0 + tx * 4 + c;
    float4 st = {1.0f - acc[0][c] * rx[0] * ry[c],
                 1.0f - acc[1][c] * rx[1] * ry[c],
                 1.0f - acc[2][c] * rx[2] * ry[c],
                 1.0f - acc[3][c] * rx[3] * ry[c]};
    *(float4*)(cb + (size_t)n * 256 + m0 + ty * 4) = st;
  }
}

// ---------------------------------------------------------------------------
// Kernel 3: forward soft-DTW, 4-ROW x 4-COLUMN block per slot.
// One wave per batch.  Lane l owns rows 4l..4l+3; at slot s it processes
// column group g = s - l (columns 4g..4g+3) -- 128 serial slots (was 319).
// Cross-lane: 4 shfl_up of lane l-1's bottom-row values (its group g,
// computed one slot earlier) + 1 carried diag.  q = R*(log2e/gv),
// stored column-major qC[b][c][r].
// ---------------------------------------------------------------------------
__device__ __forceinline__ void fwd_slot(int s, int l, const float cc[16],
                                         float pc[4], float bot[4], float& carry,
                                         float ig2, float* __restrict__ qb) {
  int g = s - l;
  bool act = (g >= 0) && (g <= 63);
  float up0 = __shfl_up(bot[0], 1);
  float up1 = __shfl_up(bot[1], 1);
  float up2 = __shfl_up(bot[2], 1);
  float up3 = __shfl_up(bot[3], 1);
  float dg0 = carry;
  carry = up3;
  if (l == 0) {
    up0 = up1 = up2 = up3 = INFV;
    dg0 = (g == 0) ? 0.0f : INFV;   // q[-1][-1] = 0 only at the origin
  }
  float up[4] = {up0, up1, up2, up3};
  float left[4];
#pragma unroll
  for (int k = 0; k < 4; ++k) left[k] = pc[k];
  float outv[16];
#pragma unroll
  for (int j = 0; j < 4; ++j) {
    float pu = up[j];                       // q[row-1][c] entering the column
    float pd = (j == 0) ? dg0 : up[j - 1];  // q[row-1][c-1]
#pragma unroll
    for (int k = 0; k < 4; ++k) {
      float a = pu, bb = left[k], c = pd;
      float mn = fminf(a, fminf(bb, c));
      float s3 = EXP2F(mn - a) + EXP2F(mn - bb) + EXP2F(mn - c);
      float v = fmaf(cc[4 * j + k], ig2, mn - LOG2F(s3));
      pd = bb; pu = v;
      outv[4 * j + k] = v;
      left[k] = v;
    }
  }
  if (act) {
#pragma unroll
    for (int k = 0; k < 4; ++k) pc[k] = left[k];
#pragma unroll
    for (int j = 0; j < 4; ++j) bot[j] = outv[4 * j + 3];
    int c0 = 4 * g;
#pragma unroll
    for (int j = 0; j < 4; ++j) {
      float4 st = {outv[4*j+0], outv[4*j+1], outv[4*j+2], outv[4*j+3]};
      *(float4*)(qb + (size_t)(c0 + j) * 256) = st;
    }
  }
}

__global__ void __launch_bounds__(64, 1) fwd_kernel(const float* __restrict__ costC,
                                                    const float* __restrict__ gamma,
                                                    float* __restrict__ qC,
                                                    float* __restrict__ dist_out) {
  int b = blockIdx.x, l = threadIdx.x;
  float gv = fmaxf(fabsf(gamma[0]), 1e-4f);
  const float LOG2E = 1.4426950408889634f;
  float ig2 = LOG2E / gv;                 // q = R * ig2
  float gl  = gv * 0.6931471805599453f;   // R = q * gl
  const float* cb = costC + (size_t)b * 65536 + 4 * l;
  float* qb = qC + (size_t)b * 65536 + 4 * l;

  float pc[4]  = {INFV, INFV, INFV, INFV};
  float bot[4] = {INFV, INFV, INFV, INFV};
  float carry  = INFV;
  float CA[16], CB[16];

  auto gptr = [&](int s) -> const float* {
    int g = min(max(s - l, 0), 63);
    return cb + (size_t)(4 * g) * 256;
  };
  auto loadC = [&](int s, float* buf) {
    const float* p = gptr(s);
#pragma unroll
    for (int j = 0; j < 4; ++j) ld4(buf + 4 * j, p + (size_t)j * 256);
  };
  loadC(0, CA);
  loadC(1, CB);
  for (int it = 0; it < 64; ++it) {   // 128 slots (last live slot = 126)
    int s = it * 2;
    fwd_slot(s, l, CA, pc, bot, carry, ig2, qb);
    loadC(s + 2, CA);
    fwd_slot(s + 1, l, CB, pc, bot, carry, ig2, qb);
    loadC(s + 3, CB);
  }
  if (l == 63) dist_out[b] = bot[3] * gl;   // q[255][255] -> R[256][256]
}

// ---------------------------------------------------------------------------
// Kernel 3.5: backward weights, tile-based, all layouts column-major.
// Boundary masking folded into weights (0).  Coalesced along r.
// ---------------------------------------------------------------------------
__global__ void __launch_bounds__(256) weights_kernel(const float* __restrict__ qC,
                                                      const float* __restrict__ costC,
                                                      const float* __restrict__ gamma,
                                                      float* __restrict__ WDc,
                                                      float* __restrict__ WNc,
                                                      float* __restrict__ WRc) {
  int b = blockIdx.z;
  int t = threadIdx.x;
  int r = blockIdx.y * 64 + (t & 63);
  int cbase = blockIdx.x * 64 + (t >> 6) * 16;
  int rp = min(r + 1, 255);
  float gv = fmaxf(fabsf(gamma[0]), 1e-4f);
  const float LOG2E = 1.4426950408889634f;
  float ig2 = LOG2E / gv;
  const float CL = 50.0f * LOG2E;
  const float* q  = qC    + (size_t)b * 65536;
  const float* co = costC + (size_t)b * 65536;
  float* wd_ = WDc + (size_t)b * 65536;
  float* wn_ = WNc + (size_t)b * 65536;
  float* wr_ = WRc + (size_t)b * 65536;
  float qcv = q[(size_t)cbase * 256 + r];
  float qnv = q[(size_t)cbase * 256 + rp];
  float cnv = co[(size_t)cbase * 256 + rp];
#pragma unroll 4
  for (int k = 0; k < 16; ++k) {
    int c = cbase + k;
    int cp = min(c + 1, 255);
    float qdv = q[(size_t)cp * 256 + rp];
    float qrv = q[(size_t)cp * 256 + r];
    float cdv = co[(size_t)cp * 256 + rp];
    float crv = co[(size_t)cp * 256 + r];
    float ad = fminf(fmaxf(fmaf(-cdv, ig2, qdv) - qcv, -CL), CL);
    float an = fminf(fmaxf(fmaf(-cnv, ig2, qnv) - qcv, -CL), CL);
    float ar = fminf(fmaxf(fmaf(-crv, ig2, qrv) - qcv, -CL), CL);
    float wd = (r < 255 && c < 255) ? EXP2F(ad) : 0.0f;
    float wn = (r < 255) ? EXP2F(an) : 0.0f;
    float wr = (c < 255) ? EXP2F(ar) : 0.0f;
    size_t o = (size_t)c * 256 + r;
    wd_[o] = wd; wn_[o] = wn; wr_[o] = wr;
    qcv = qrv; qnv = qdv; cnv = cdv;
  }
}

// ---------------------------------------------------------------------------
// Kernel 4: backward recurrence, 4-ROW x 4-COLUMN block per slot, right->left.
//   E[r][c] = E[r+1][c+1]*wd + E[r+1][c]*wn + E[r][c+1]*wr,  E[255][255]=1.
// Lane l owns rows 4l..4l+3; at slot s processes group g = s - (63-l)
// (columns 255-4g down to 252-4g).  Lane l+1 computed the same columns one
// slot earlier -> 4 shfl_down of its top-row values + 1 carried diag.
// 129 serial slots (was 319); weights via 3-deep group FIFO (12 columns /
// 36 float4 loads in flight -> covers ~900 cyc latency).
// ---------------------------------------------------------------------------
__device__ __forceinline__ void bwd_slot(int s, int l,
    const float wd[16], const float wn[16], const float wr[16],
    float right[4], float top[4], float& carry, float* __restrict__ Eb) {
  int g = s - (63 - l);
  bool act = (g >= 0) && (g <= 63);
  float dt0 = __shfl_down(top[0], 1);
  float dt1 = __shfl_down(top[1], 1);
  float dt2 = __shfl_down(top[2], 1);
  float dt3 = __shfl_down(top[3], 1);
  float dg0 = carry;
  carry = dt3;
  if (l == 63) { dt0 = dt1 = dt2 = dt3 = 0.0f; dg0 = 0.0f; }
  float dt[4] = {dt0, dt1, dt2, dt3};
  float rgt[4];
#pragma unroll
  for (int k = 0; k < 4; ++k) rgt[k] = right[k];
  float outv[16];
#pragma unroll
  for (int j = 0; j < 4; ++j) {            // column c = 255 - 4g - j
    float dn  = dt[j];                     // E[row+1][c] entering (bottom-up)
    float drt = (j == 0) ? dg0 : dt[j - 1];// E[row+1][c+1]
#pragma unroll
    for (int k = 3; k >= 0; --k) {
      float rt = rgt[k];                   // E[r][c+1]
      float v = drt * wd[4*j+k] + dn * wn[4*j+k] + rt * wr[4*j+k];
      if (l == 63 && j == 0 && k == 3 && g == 0) v = 1.0f;  // seed E[255][255]
      drt = rt; dn = v;
      outv[4*j+k] = v;
      rgt[k] = v;
    }
  }
  if (act) {
#pragma unroll
    for (int k = 0; k < 4; ++k) right[k] = rgt[k];
#pragma unroll
    for (int j = 0; j < 4; ++j) top[j] = outv[4*j + 0];
    int cb0 = 255 - 4 * g;
#pragma unroll
    for (int j = 0; j < 4; ++j) {
      float4 st = {outv[4*j+0], outv[4*j+1], outv[4*j+2], outv[4*j+3]};
      *(float4*)(Eb + (size_t)(cb0 - j) * 256) = st;
    }
  }
}

__global__ void __launch_bounds__(64, 1) bwd_kernel(const float* __restrict__ WDc,
                                                    const float* __restrict__ WNc,
                                                    const float* __restrict__ WRc,
                                                    float* __restrict__ EC) {
  int b = blockIdx.x, l = threadIdx.x;
  const float* wdb = WDc + (size_t)b * 65536 + 4 * l;
  const float* wnb = WNc + (size_t)b * 65536 + 4 * l;
  const float* wrb = WRc + (size_t)b * 65536 + 4 * l;
  float* Eb = EC + (size_t)b * 65536 + 4 * l;
  float right[4] = {0.f, 0.f, 0.f, 0.f};
  float top[4]   = {0.f, 0.f, 0.f, 0.f};
  float carry = 0.0f;
  float Da[16], Na[16], Ra[16];
  float Db[16], Nb[16], Rb[16];
  float Dc[16], Nc[16], Rc[16];
  auto loadW = [&](int s, float* D, float* N, float* R) {
    int g = min(max(s - (63 - l), 0), 63);
    size_t off = (size_t)(255 - 4 * g) * 256;
#pragma unroll
    for (int j = 0; j < 4; ++j) {
      ld4(D + 4*j, wdb + off - (size_t)j * 256);
      ld4(N + 4*j, wnb + off - (size_t)j * 256);
      ld4(R + 4*j, wrb + off - (size_t)j * 256);
    }
  };
  loadW(0, Da, Na, Ra);
  loadW(1, Db, Nb, Rb);
  loadW(2, Dc, Nc, Rc);
  for (int it = 0; it < 43; ++it) {   // 129 slots (last live slot = 126)
    int s = it * 3;
    bwd_slot(s + 0, l, Da, Na, Ra, right, top, carry, Eb);
    loadW(s + 3, Da, Na, Ra);
    bwd_slot(s + 1, l, Db, Nb, Rb, right, top, carry, Eb);
    loadW(s + 4, Db, Nb, Rb);
    bwd_slot(s + 2, l, Dc, Nc, Rc, right, top, carry, Eb);
    loadW(s + 5, Dc, Nc, Rc);
  }
}

// ---------------------------------------------------------------------------
// Kernel 5: plain 2D transpose: out[b][m][n] = EC[b][n*256 + m].
// ---------------------------------------------------------------------------
__global__ void __launch_bounds__(256) transpose_kernel(const float* __restrict__ EC,
                                                        float* __restrict__ out) {
  int b = blockIdx.z, mt = blockIdx.y, nt = blockIdx.x;
  int m0 = mt * 64, n0 = nt * 64;
  __shared__ float T[64][65];
  const float* Eb = EC + (size_t)b * 65536;
  for (int k = threadIdx.x; k < 4096; k += 256) {
    int nn = k >> 6, mm = k & 63;
    T[nn][mm] = Eb[(size_t)(n0 + nn) * 256 + m0 + mm];
  }
  __syncthreads();
  float* ob = out + ((size_t)b * 256 + m0) * 256 + n0;
  for (int k = threadIdx.x; k < 4096; k += 256) {
    int r = k >> 6, c = k & 63;
    ob[(size_t)r * 256 + c] = T[c][r];
  }
}

// ---------------------------------------------------------------------------
// Workspace layout (floats), ~12.6 MB (column-major, 65536/batch, stride 256):
//   rnx @ 0 (2048) | rny @ 2048 (2048) | costC @ 4096 | qC | WDc | WNc | WRc | EC
// d_out: alignment [0 .. 524287], distance [524288 .. 524295].
// ---------------------------------------------------------------------------
extern "C" void kernel_launch(void* const* d_in, const int* in_sizes, int n_in,
                              void* d_out, int out_size, void* d_ws, size_t ws_size,
                              hipStream_t stream) {
  const float* x = (const float*)d_in[0];
  const float* y = (const float*)d_in[1];
  const float* gamma = (const float*)d_in[2];
  float* out = (float*)d_out;
  float* ws = (float*)d_ws;

  const size_t MAT = (size_t)8 * 65536;
  float* rnx   = ws;
  float* rny   = ws + 2048;
  float* costC = ws + 4096;
  float* qC    = costC + MAT;
  float* WDc   = qC    + MAT;
  float* WNc   = WDc   + MAT;
  float* WRc   = WNc   + MAT;
  float* EC    = WRc   + MAT;

  norms_kernel<<<1024, 256, 0, stream>>>(x, y, rnx, rny);
  cost_gemm<<<dim3(4, 4, 8), 256, 0, stream>>>(x, y, rnx, rny, costC);
  fwd_kernel<<<8, 64, 0, stream>>>(costC, gamma, qC, out + 524288);
  weights_kernel<<<dim3(4, 4, 8), 256, 0, stream>>>(qC, costC, gamma, WDc, WNc, WRc);
  bwd_kernel<<<8, 64, 0, stream>>>(WDc, WNc, WRc, EC);
  transpose_kernel<<<dim3(4, 4, 8), 256, 0, stream>>>(EC, out);
}

// Round 7
// 248.741 us; speedup vs baseline: 1.0586x; 1.0586x over previous
//
#include <hip/hip_runtime.h>

// Problem constants: B=8, M=N=256, D=512
#define INFV 1.0e8f

// Raw HW transcendentals: v_exp_f32 is 2^x, v_log_f32 is log2(x).
#define EXP2F(x) __builtin_amdgcn_exp2f(x)
#define LOG2F(x) __builtin_amdgcn_logf(x)

// Block-diagonal layout: 4x4 cell blocks (I,J), I,J in [0,64).
// chunk s = I+J in [0,127); tensor[b][s][I][16], idx-in-block = j*4+k
// (j = col 0..3 left->right, k = row 0..3 top->down).
// Chunk = 64 blocks * 16 f = 1024 floats; 128 chunks/batch (s=127 pad).
#define CHUNK 1024
#define BSTRIDE 131072   // floats per batch per tensor

__device__ __forceinline__ void ld4(float d[4], const float* p) {
  float4 v = *(const float4*)p;
  d[0] = v.x; d[1] = v.y; d[2] = v.z; d[3] = v.w;
}

// ---------------------------------------------------------------------------
// Kernel 1: inverse row norms.  rn = 1 / max(||row||, 1e-8)
// ---------------------------------------------------------------------------
__global__ void __launch_bounds__(256) norms_kernel(const float* __restrict__ x,
                                                    const float* __restrict__ y,
                                                    float* __restrict__ rnx,
                                                    float* __restrict__ rny) {
  int g = blockIdx.x * 4 + (threadIdx.x >> 6);
  int lane = threadIdx.x & 63;
  const float* src; float* dst; int row;
  if (g < 2048) { src = x; dst = rnx; row = g; }
  else          { src = y; dst = rny; row = g - 2048; }
  const float* p = src + (size_t)row * 512;
  float4 v0 = *(const float4*)(p + lane * 4);
  float4 v1 = *(const float4*)(p + 256 + lane * 4);
  float s = v0.x*v0.x + v0.y*v0.y + v0.z*v0.z + v0.w*v0.w
          + v1.x*v1.x + v1.y*v1.y + v1.z*v1.z + v1.w*v1.w;
#pragma unroll
  for (int o = 32; o > 0; o >>= 1) s += __shfl_xor(s, o, 64);
  if (lane == 0) dst[row] = 1.0f / fmaxf(sqrtf(s), 1e-8f);
}

// ---------------------------------------------------------------------------
// Kernel 2: cost GEMM -> BLOCK-DIAG layout.  Each thread's 4x4 micro-tile is
// exactly one (I,J) block -> 64 B contiguous epilogue store per thread.
// ---------------------------------------------------------------------------
__global__ void __launch_bounds__(256) cost_gemm(const float* __restrict__ x,
                                                 const float* __restrict__ y,
                                                 const float* __restrict__ rnx,
                                                 const float* __restrict__ rny,
                                                 float* __restrict__ costB) {
  int b = blockIdx.z, mt = blockIdx.y, nt = blockIdx.x;
  int m0 = mt * 64, n0 = nt * 64;
  __shared__ float Xs[16][68];
  __shared__ float Ys[16][68];
  int tid = threadIdx.x;
  int row = tid >> 2, cq = tid & 3;
  int tx = tid & 15, ty = tid >> 4;
  const float* xb = x + ((size_t)b * 256 + m0) * 512;
  const float* yb = y + ((size_t)b * 256 + n0) * 512;
  float acc[4][4] = {};
  for (int k0 = 0; k0 < 512; k0 += 16) {
    float4 xv = *(const float4*)(xb + (size_t)row * 512 + k0 + cq * 4);
    float4 yv = *(const float4*)(yb + (size_t)row * 512 + k0 + cq * 4);
    __syncthreads();
    Xs[cq*4+0][row] = xv.x; Xs[cq*4+1][row] = xv.y;
    Xs[cq*4+2][row] = xv.z; Xs[cq*4+3][row] = xv.w;
    Ys[cq*4+0][row] = yv.x; Ys[cq*4+1][row] = yv.y;
    Ys[cq*4+2][row] = yv.z; Ys[cq*4+3][row] = yv.w;
    __syncthreads();
#pragma unroll
    for (int kk = 0; kk < 16; ++kk) {
      float4 av = *(const float4*)(&Xs[kk][ty * 4]);
      float4 bv = *(const float4*)(&Ys[kk][tx * 4]);
      float ar[4] = {av.x, av.y, av.z, av.w};
      float br[4] = {bv.x, bv.y, bv.z, bv.w};
#pragma unroll
      for (int r = 0; r < 4; ++r)
#pragma unroll
        for (int c = 0; c < 4; ++c)
          acc[r][c] += ar[r] * br[c];
    }
  }
  float rx[4], ry[4];
#pragma unroll
  for (int r = 0; r < 4; ++r) rx[r] = rnx[b * 256 + m0 + ty * 4 + r];
#pragma unroll
  for (int c = 0; c < 4; ++c) ry[c] = rny[b * 256 + n0 + tx * 4 + c];
  int I = mt * 16 + ty, J = nt * 16 + tx;
  float* bp = costB + (size_t)b * BSTRIDE + ((size_t)(I + J) * 64 + I) * 16;
#pragma unroll
  for (int c = 0; c < 4; ++c) {
    float4 st = {1.0f - acc[0][c] * rx[0] * ry[c],
                 1.0f - acc[1][c] * rx[1] * ry[c],
                 1.0f - acc[2][c] * rx[2] * ry[c],
                 1.0f - acc[3][c] * rx[3] * ry[c]};
    *(float4*)(bp + c * 4) = st;
  }
}

// ---------------------------------------------------------------------------
// Kernel 3: forward soft-DTW, block-diag traversal.  One wave per batch;
// lane l owns row-strip I=l; at slot s processes block (l, s-l).  The whole
// wave reads cost chunk s (dense 4 KB) and writes q chunk s.  q = R*log2e/gv.
// ---------------------------------------------------------------------------
__device__ __forceinline__ void fwd_slot(int s, int l, const float cc[16],
                                         float pc[4], float bot[4], float& carry,
                                         float ig2, float* __restrict__ qBb) {
  int g = s - l;
  bool act = (g >= 0) && (g <= 63);
  float up0 = __shfl_up(bot[0], 1);
  float up1 = __shfl_up(bot[1], 1);
  float up2 = __shfl_up(bot[2], 1);
  float up3 = __shfl_up(bot[3], 1);
  float dg0 = carry;
  carry = up3;
  if (l == 0) { up0 = up1 = up2 = up3 = INFV; dg0 = (g == 0) ? 0.0f : INFV; }
  float up[4] = {up0, up1, up2, up3};
  float left[4];
#pragma unroll
  for (int k = 0; k < 4; ++k) left[k] = pc[k];
  float outv[16];
#pragma unroll
  for (int j = 0; j < 4; ++j) {
    float pu = up[j];                       // q[row-1][col] entering column
    float pd = (j == 0) ? dg0 : up[j - 1];  // q[row-1][col-1]
#pragma unroll
    for (int k = 0; k < 4; ++k) {
      float a = pu, bb = left[k], c = pd;
      float mn = fminf(a, fminf(bb, c));
      float s3 = EXP2F(mn - a) + EXP2F(mn - bb) + EXP2F(mn - c);
      float v = fmaf(cc[j * 4 + k], ig2, mn - LOG2F(s3));
      pd = bb; pu = v;
      outv[j * 4 + k] = v;
      left[k] = v;
    }
  }
  if (act) {
#pragma unroll
    for (int k = 0; k < 4; ++k) pc[k] = left[k];
#pragma unroll
    for (int j = 0; j < 4; ++j) bot[j] = outv[j * 4 + 3];
    float* bp = qBb + (size_t)s * CHUNK + l * 16;
#pragma unroll
    for (int j = 0; j < 4; ++j) {
      float4 st = {outv[4*j+0], outv[4*j+1], outv[4*j+2], outv[4*j+3]};
      *(float4*)(bp + 4 * j) = st;
    }
  }
}

__global__ void __launch_bounds__(64, 1) fwd_kernel(const float* __restrict__ costB,
                                                    const float* __restrict__ gamma,
                                                    float* __restrict__ qBuf,
                                                    float* __restrict__ dist_out) {
  int b = blockIdx.x, l = threadIdx.x;
  float gv = fmaxf(fabsf(gamma[0]), 1e-4f);
  const float LOG2E = 1.4426950408889634f;
  float ig2 = LOG2E / gv;                 // q = R * ig2
  float gl  = gv * 0.6931471805599453f;   // R = q * gl
  const float* cbB = costB + (size_t)b * BSTRIDE;
  float* qBb = qBuf + (size_t)b * BSTRIDE;
  float pc[4]  = {INFV, INFV, INFV, INFV};
  float bot[4] = {INFV, INFV, INFV, INFV};
  float carry  = INFV;
  float C0[16], C1[16], C2[16];
  auto loadC = [&](int s, float* buf) {
    const float* p = cbB + (size_t)min(s, 127) * CHUNK + l * 16;
    ld4(buf, p); ld4(buf + 4, p + 4); ld4(buf + 8, p + 8); ld4(buf + 12, p + 12);
  };
  loadC(0, C0); loadC(1, C1); loadC(2, C2);
  for (int it = 0; it < 43; ++it) {   // 129 slots; last live slot = 126
    int s = it * 3;
    fwd_slot(s + 0, l, C0, pc, bot, carry, ig2, qBb);
    loadC(s + 3, C0);
    fwd_slot(s + 1, l, C1, pc, bot, carry, ig2, qBb);
    loadC(s + 4, C1);
    fwd_slot(s + 2, l, C2, pc, bot, carry, ig2, qBb);
    loadC(s + 5, C2);
  }
  if (l == 63) dist_out[b] = bot[3] * gl;   // q[255][255] -> R[256][256]
}

// ---------------------------------------------------------------------------
// Kernel 3.5: backward weights, one thread per target block (I,J).
// Reads q & cost blocks (I,J),(I+1,J),(I,J+1),(I+1,J+1) (64 B lines each),
// writes WD/WN/WR blocks (I,J).  Boundary masking folded in (w=0).
// ---------------------------------------------------------------------------
__global__ void __launch_bounds__(256) weights_kernel(const float* __restrict__ qBuf,
                                                      const float* __restrict__ costB,
                                                      const float* __restrict__ gamma,
                                                      float* __restrict__ WD,
                                                      float* __restrict__ WN,
                                                      float* __restrict__ WR) {
  int b = blockIdx.y;
  int tb = blockIdx.x * 256 + threadIdx.x;   // 0..4095
  int J = tb & 63, I = tb >> 6;
  float gv = fmaxf(fabsf(gamma[0]), 1e-4f);
  const float LOG2E = 1.4426950408889634f;
  float ig2 = LOG2E / gv;
  const float CL = 50.0f * LOG2E;
  const float* qb = qBuf  + (size_t)b * BSTRIDE;
  const float* cb = costB + (size_t)b * BSTRIDE;
  auto bo = [](int i, int j) { return ((size_t)(i + j) * 64 + i) * 16; };
  int Ic = min(I + 1, 63), Jc = min(J + 1, 63);
  float qA[16], qBk[16], qCk[16], qDk[16], cA[16], cBk[16], cCk[16], cDk[16];
  {
    const float* p;
    p = qb + bo(I, J);   ld4(qA, p); ld4(qA+4, p+4); ld4(qA+8, p+8); ld4(qA+12, p+12);
    p = qb + bo(Ic, J);  ld4(qBk, p); ld4(qBk+4, p+4); ld4(qBk+8, p+8); ld4(qBk+12, p+12);
    p = qb + bo(I, Jc);  ld4(qCk, p); ld4(qCk+4, p+4); ld4(qCk+8, p+8); ld4(qCk+12, p+12);
    p = qb + bo(Ic, Jc); ld4(qDk, p); ld4(qDk+4, p+4); ld4(qDk+8, p+8); ld4(qDk+12, p+12);
    p = cb + bo(I, J);   ld4(cA, p); ld4(cA+4, p+4); ld4(cA+8, p+8); ld4(cA+12, p+12);
    p = cb + bo(Ic, J);  ld4(cBk, p); ld4(cBk+4, p+4); ld4(cBk+8, p+8); ld4(cBk+12, p+12);
    p = cb + bo(I, Jc);  ld4(cCk, p); ld4(cCk+4, p+4); ld4(cCk+8, p+8); ld4(cCk+12, p+12);
    p = cb + bo(Ic, Jc); ld4(cDk, p); ld4(cDk+4, p+4); ld4(cDk+8, p+8); ld4(cDk+12, p+12);
  }
  float od[16], on[16], orr[16];
#pragma unroll
  for (int j = 0; j < 4; ++j) {
#pragma unroll
    for (int k = 0; k < 4; ++k) {
      float q_c = qA[j*4+k];
      float q_n = (k < 3) ? qA[j*4+k+1] : qBk[j*4+0];
      float q_r = (j < 3) ? qA[(j+1)*4+k] : qCk[k];
      float q_d = (k < 3) ? ((j < 3) ? qA[(j+1)*4+k+1] : qCk[k+1])
                          : ((j < 3) ? qBk[(j+1)*4+0] : qDk[0]);
      float c_n = (k < 3) ? cA[j*4+k+1] : cBk[j*4+0];
      float c_r = (j < 3) ? cA[(j+1)*4+k] : cCk[k];
      float c_d = (k < 3) ? ((j < 3) ? cA[(j+1)*4+k+1] : cCk[k+1])
                          : ((j < 3) ? cBk[(j+1)*4+0] : cDk[0]);
      float ad = fminf(fmaxf(fmaf(-c_d, ig2, q_d) - q_c, -CL), CL);
      float an = fminf(fmaxf(fmaf(-c_n, ig2, q_n) - q_c, -CL), CL);
      float ar = fminf(fmaxf(fmaf(-c_r, ig2, q_r) - q_c, -CL), CL);
      bool rm = !(I == 63 && k == 3);   // r < 255
      bool cm = !(J == 63 && j == 3);   // c < 255
      od[j*4+k]  = (rm && cm) ? EXP2F(ad) : 0.0f;
      on[j*4+k]  = rm ? EXP2F(an) : 0.0f;
      orr[j*4+k] = cm ? EXP2F(ar) : 0.0f;
    }
  }
  size_t o = (size_t)b * BSTRIDE + bo(I, J);
#pragma unroll
  for (int j = 0; j < 4; ++j) {
    *(float4*)(WD + o + 4*j) = *(float4*)(od + 4*j);
    *(float4*)(WN + o + 4*j) = *(float4*)(on + 4*j);
    *(float4*)(WR + o + 4*j) = *(float4*)(orr + 4*j);
  }
}

// ---------------------------------------------------------------------------
// Kernel 4: backward recurrence, block-diag, right->left/bottom->up.
//   E[r][c] = E[r+1][c+1]*wd + E[r+1][c]*wn + E[r][c+1]*wr,  E[255][255]=1.
// Lane l owns strip I=l; at slot u processes block (l, 126-u-l).  Whole wave
// reads weight chunks 126-u (3 dense 4 KB) and writes E chunk 126-u.
// ---------------------------------------------------------------------------
__device__ __forceinline__ void bwd_slot(int u, int l,
    const float wd[16], const float wn[16], const float wr[16],
    float right[4], float top[4], float& carry, float* __restrict__ EBb) {
  int J = 126 - u - l;
  bool act = (J >= 0) && (J <= 63);
  float dt0 = __shfl_down(top[0], 1);
  float dt1 = __shfl_down(top[1], 1);
  float dt2 = __shfl_down(top[2], 1);
  float dt3 = __shfl_down(top[3], 1);
  float dgc = carry;
  carry = dt0;                 // next slot's below-right corner = this dt[0]
  if (l == 63) { dt0 = dt1 = dt2 = dt3 = 0.0f; dgc = 0.0f; }
  float dt[4] = {dt0, dt1, dt2, dt3};
  float colR[4];
#pragma unroll
  for (int k = 0; k < 4; ++k) colR[k] = right[k];
  float outv[16];
#pragma unroll
  for (int j = 3; j >= 0; --j) {
    float dn  = dt[j];                       // E[row+1][col j] (bottom-up)
    float drt = (j == 3) ? dgc : dt[j + 1];  // E[row+1][col j+1]
#pragma unroll
    for (int k = 3; k >= 0; --k) {
      float rt = colR[k];                    // E[row][col j+1]
      float v = drt * wd[j*4+k] + dn * wn[j*4+k] + rt * wr[j*4+k];
      if (l == 63 && J == 63 && j == 3 && k == 3) v = 1.0f;  // seed E[255][255]
      drt = rt; dn = v;
      outv[j*4+k] = v;
    }
#pragma unroll
    for (int k = 0; k < 4; ++k) colR[k] = outv[j*4+k];
  }
  if (act) {
#pragma unroll
    for (int k = 0; k < 4; ++k) right[k] = colR[k];
#pragma unroll
    for (int j = 0; j < 4; ++j) top[j] = outv[j*4+0];
    float* bp = EBb + (size_t)(126 - u) * CHUNK + l * 16;
#pragma unroll
    for (int j = 0; j < 4; ++j) {
      float4 st = {outv[4*j+0], outv[4*j+1], outv[4*j+2], outv[4*j+3]};
      *(float4*)(bp + 4 * j) = st;
    }
  }
}

__global__ void __launch_bounds__(64, 1) bwd_kernel(const float* __restrict__ WD,
                                                    const float* __restrict__ WN,
                                                    const float* __restrict__ WR,
                                                    float* __restrict__ EB) {
  int b = blockIdx.x, l = threadIdx.x;
  const float* wdb = WD + (size_t)b * BSTRIDE + l * 16;
  const float* wnb = WN + (size_t)b * BSTRIDE + l * 16;
  const float* wrb = WR + (size_t)b * BSTRIDE + l * 16;
  float* EBb = EB + (size_t)b * BSTRIDE;
  float right[4] = {0.f, 0.f, 0.f, 0.f};
  float top[4]   = {0.f, 0.f, 0.f, 0.f};
  float carry = 0.0f;
  float Da[16], Na[16], Ra[16];
  float Db[16], Nb[16], Rb[16];
  float Dc[16], Nc[16], Rc[16];
  auto loadW = [&](int u, float* D, float* N, float* R) {
    size_t off = (size_t)max(126 - u, 0) * CHUNK;
    const float* pd = wdb + off; const float* pn = wnb + off; const float* pr = wrb + off;
    ld4(D, pd); ld4(D+4, pd+4); ld4(D+8, pd+8); ld4(D+12, pd+12);
    ld4(N, pn); ld4(N+4, pn+4); ld4(N+8, pn+8); ld4(N+12, pn+12);
    ld4(R, pr); ld4(R+4, pr+4); ld4(R+8, pr+8); ld4(R+12, pr+12);
  };
  loadW(0, Da, Na, Ra);
  loadW(1, Db, Nb, Rb);
  loadW(2, Dc, Nc, Rc);
  for (int it = 0; it < 43; ++it) {   // 129 slots; last live slot = 126
    int u = it * 3;
    bwd_slot(u + 0, l, Da, Na, Ra, right, top, carry, EBb);
    loadW(u + 3, Da, Na, Ra);
    bwd_slot(u + 1, l, Db, Nb, Rb, right, top, carry, EBb);
    loadW(u + 4, Db, Nb, Rb);
    bwd_slot(u + 2, l, Dc, Nc, Rc, right, top, carry, EBb);
    loadW(u + 5, Dc, Nc, Rc);
  }
}

// ---------------------------------------------------------------------------
// Kernel 5: block-diag -> row-major.  out[b][4I+k][4J+j] = EB block (I,J)[j*4+k].
// 64x64 output tile per HIP block; padded LDS (17 floats/block slot).
// ---------------------------------------------------------------------------
__global__ void __launch_bounds__(256) transpose_kernel(const float* __restrict__ EB,
                                                        float* __restrict__ out) {
  int b = blockIdx.z, mt = blockIdx.y, nt = blockIdx.x;
  __shared__ float T[16 * 16 * 17];
  const float* Eb = EB + (size_t)b * BSTRIDE;
  int t = threadIdx.x;
  int Ii = mt * 16 + (t >> 4), Jj = nt * 16 + (t & 15);
  const float* bp = Eb + ((size_t)(Ii + Jj) * 64 + Ii) * 16;
  float* dst = &T[((t >> 4) * 16 + (t & 15)) * 17];
  float tmp[16];
  ld4(tmp, bp); ld4(tmp+4, bp+4); ld4(tmp+8, bp+8); ld4(tmp+12, bp+12);
#pragma unroll
  for (int q = 0; q < 16; ++q) dst[q] = tmp[q];
  __syncthreads();
  float* ob = out + ((size_t)b * 256 + mt * 64) * 256 + nt * 64;
#pragma unroll
  for (int it = 0; it < 16; ++it) {
    int lin = it * 256 + t;
    int mm = lin >> 6, nn = lin & 63;
    int Ib = mm >> 2, k = mm & 3, Jb = nn >> 2, j = nn & 3;
    ob[(size_t)mm * 256 + nn] = T[(Ib * 16 + Jb) * 17 + j * 4 + k];
  }
}

// ---------------------------------------------------------------------------
// Workspace (floats), ~21.0 MB:
//   rnx @ 0 (2048) | rny @ 2048 (2048)
//   costB @ 4096 (8*131072)  [aliased as EB by bwd -- cost dead after weights]
//   qB | WD | WN | WR  (each 8*131072)
// d_out: alignment [0 .. 524287], distance [524288 .. 524295].
// ---------------------------------------------------------------------------
extern "C" void kernel_launch(void* const* d_in, const int* in_sizes, int n_in,
                              void* d_out, int out_size, void* d_ws, size_t ws_size,
                              hipStream_t stream) {
  const float* x = (const float*)d_in[0];
  const float* y = (const float*)d_in[1];
  const float* gamma = (const float*)d_in[2];
  float* out = (float*)d_out;
  float* ws = (float*)d_ws;

  const size_t MAT = (size_t)8 * BSTRIDE;
  float* rnx   = ws;
  float* rny   = ws + 2048;
  float* costB = ws + 4096;
  float* qB    = costB + MAT;
  float* WDp   = qB    + MAT;
  float* WNp   = WDp   + MAT;
  float* WRp   = WNp   + MAT;
  float* EB    = costB;   // alias: costB dead after weights_kernel

  norms_kernel<<<1024, 256, 0, stream>>>(x, y, rnx, rny);
  cost_gemm<<<dim3(4, 4, 8), 256, 0, stream>>>(x, y, rnx, rny, costB);
  fwd_kernel<<<8, 64, 0, stream>>>(costB, gamma, qB, out + 524288);
  weights_kernel<<<dim3(16, 8), 256, 0, stream>>>(qB, costB, gamma, WDp, WNp, WRp);
  bwd_kernel<<<8, 64, 0, stream>>>(WDp, WNp, WRp, EB);
  transpose_kernel<<<dim3(4, 4, 8), 256, 0, stream>>>(EB, out);
}